// Round 1
// 136.603 us; speedup vs baseline: 1.0032x; 1.0032x over previous
//
#include <hip/hip_runtime.h>
#include <hip/hip_bf16.h>
#include <math.h>

#define B_ 4
#define S_ 2048
#define E_ 1024
#define H_ 64
#define NQT 32          // S/64 q-tiles
#define SPLITS 8
#define TPS 4           // 64-key tiles per split (256 keys/split)

typedef short bf16x8 __attribute__((ext_vector_type(8)));
typedef float f32x4 __attribute__((ext_vector_type(4)));
typedef unsigned short u16x8 __attribute__((ext_vector_type(8)));
typedef unsigned short u16x4 __attribute__((ext_vector_type(4)));

__device__ __forceinline__ unsigned short f2bf(float f){
    unsigned u = __builtin_bit_cast(unsigned, f);
    u += 0x7fffu + ((u >> 16) & 1u);          // RNE
    return (unsigned short)(u >> 16);
}
__device__ __forceinline__ float bf2f(unsigned short h){
    return __builtin_bit_cast(float, ((unsigned)h) << 16);
}
#define MFMA16(a,b,c) __builtin_amdgcn_mfma_f32_16x16x32_bf16((a),(b),(c),0,0,0)

__device__ __forceinline__ void gload_lds16(const void* g, void* l){
    __builtin_amdgcn_global_load_lds((const __attribute__((address_space(1))) unsigned int*)g,
                                     (__attribute__((address_space(3))) unsigned int*)l, 16, 0, 0);
}

// ---------------------------------------------------------------------------
// Kernel 0: W prep.  Wq|Wk|Wv fp32 [64][1024] -> hi/lo bf16 [192][1024] with
// the XOR bank-swizzle PRE-APPLIED in the global layout:
//   WhiS[n][kg] = f2bf(W[n][(kg & ~7) | ((kg & 7) ^ (n & 7))])
// so the GEMM can stage B with linear global_load_lds and read fragments with
// the usual (chunk ^ (row&7)) XOR.  Run once: 24576 threads.
// ---------------------------------------------------------------------------
__global__ __launch_bounds__(256) void wprep_kernel(
    const float* __restrict__ Wq, const float* __restrict__ Wk,
    const float* __restrict__ Wv,
    unsigned short* __restrict__ WhiS, unsigned short* __restrict__ WloS)
{
    const int gid = blockIdx.x*256 + threadIdx.x;     // 192*128 = 24576 tasks
    const int n = gid >> 7, g = gid & 127;            // row, u16x8-group
    const float* W = (n < 64)  ? (Wq + (size_t)n*E_)
                   : (n < 128) ? (Wk + (size_t)(n-64)*E_)
                               : (Wv + (size_t)(n-128)*E_);
    const int gs = (g & ~7) | ((g & 7) ^ (n & 7));    // swizzled source group
    const float* src = W + gs*8;
    float4 a = ((const float4*)src)[0];
    float4 b = ((const float4*)src)[1];
    float vv[8] = {a.x,a.y,a.z,a.w,b.x,b.y,b.z,b.w};
    u16x8 hv, lv;
    #pragma unroll
    for (int j=0;j<8;j++){ unsigned short h = f2bf(vv[j]); hv[j]=h; lv[j]=f2bf(vv[j]-bf2f(h)); }
    ((u16x8*)WhiS)[n*128 + g] = hv;
    ((u16x8*)WloS)[n*128 + g] = lv;
}

// ---------------------------------------------------------------------------
// Kernel 1: fused QKV projection.  C[8192 x 192] = x[8192x1024] @ Wcat^T.
// M-tile 32 (grid 256 = 1 block/CU), N=192 covers Q|K|V in one pass: x is
// read from HBM exactly once.  B (W hi/lo) staged via global_load_lds from
// the pre-swizzled WhiS/WloS (zero staging VALU); only the 32x64 x-tile is
// converted fp32->hi/lo bf16 in-kernel (8 floats/thread/k-step).
// hi*hi + hi*lo + lo*hi MFMA passes -> fp32-accurate results (same numerics
// as before).  4 waves: wave w owns cols [48w, 48w+48) = 3 n-tiles, 2 m-tiles.
// ---------------------------------------------------------------------------
__global__ __launch_bounds__(256) void qkv_kernel(
    const float* __restrict__ x,
    const unsigned short* __restrict__ WhiS, const unsigned short* __restrict__ WloS,
    unsigned short* __restrict__ Qhi, unsigned short* __restrict__ Qlo,
    unsigned short* __restrict__ Khi, unsigned short* __restrict__ Klo,
    unsigned short* __restrict__ Vt)
{
    __shared__ unsigned short Ah[32*64], Al[32*64];    // 4 KB each
    __shared__ unsigned short Bh[192*64], Bl[192*64];  // 24 KB each (56 KB total)
    const int m0 = blockIdx.x * 32;
    const int tid = threadIdx.x;
    const int lane = tid & 63, wv = tid >> 6, l15 = lane & 15, quad = lane >> 4;

    f32x4 acc[2][3];
    #pragma unroll
    for (int mt=0;mt<2;mt++)
    #pragma unroll
    for (int nt=0;nt<3;nt++) acc[mt][nt] = f32x4{0.f,0.f,0.f,0.f};

    // A staging: thread handles 8 fp32 of row (tid>>3), group (tid&7)
    const int arow = tid >> 3;          // 0..31
    const int ag   = tid & 7;
    // B staging: wave wv stages 96 rows of (wv<2 ? Bh : Bl) starting at (wv&1)*96
    unsigned short* tbuf = (wv < 2) ? Bh : Bl;
    const unsigned short* gsrc = (wv < 2) ? WhiS : WloS;
    const int rbase0 = (wv & 1) * 96;
    const int lrow = lane >> 3, lgrp = lane & 7;       // within an 8-row slab

    for (int k0 = 0; k0 < E_; k0 += 64) {
        // x tile -> regs (global only; overlaps with previous iter's MFMA)
        const float* xs = x + (size_t)(m0 + arow)*E_ + k0 + ag*8;
        float4 xa = ((const float4*)xs)[0];
        float4 xb = ((const float4*)xs)[1];
        __syncthreads();                 // previous iter's fragment reads done
        // --- B stage: 12 x global_load_lds(16B) per wave, linear LDS dest ---
        #pragma unroll
        for (int i = 0; i < 12; i++) {
            const int rb = rbase0 + i*8;
            const unsigned short* gp = gsrc + (size_t)(rb + lrow)*E_ + k0 + lgrp*8;
            gload_lds16(gp, tbuf + rb*64);
        }
        // --- A stage: convert 8 fp32 -> hi/lo bf16, XOR-swizzled LDS write ---
        {
            float vv[8] = {xa.x,xa.y,xa.z,xa.w,xb.x,xb.y,xb.z,xb.w};
            u16x8 hv, lv;
            #pragma unroll
            for (int j=0;j<8;j++){ unsigned short h = f2bf(vv[j]); hv[j]=h; lv[j]=f2bf(vv[j]-bf2f(h)); }
            const int idx = arow*8 + (ag ^ (arow & 7));
            ((u16x8*)Ah)[idx] = hv; ((u16x8*)Al)[idx] = lv;
        }
        __syncthreads();                 // drains gll (vmcnt) + A ds_writes
        // --- MFMA: 2 mt x 3 nt x 2 kk x 3 passes = 36 per wave per k-step ---
        #pragma unroll
        for (int kk=0; kk<2; kk++){
            const int xr = (kk*4+quad) ^ (l15 & 7);
            bf16x8 ah[2], al[2];
            #pragma unroll
            for (int mt=0; mt<2; mt++){
                const int arw = mt*16 + l15;
                ah[mt] = ((const bf16x8*)Ah)[arw*8 + xr];
                al[mt] = ((const bf16x8*)Al)[arw*8 + xr];
            }
            #pragma unroll
            for (int nt=0; nt<3; nt++){
                const int brw = wv*48 + nt*16 + l15;
                bf16x8 bh = ((const bf16x8*)Bh)[brw*8 + xr];
                bf16x8 bl = ((const bf16x8*)Bl)[brw*8 + xr];
                #pragma unroll
                for (int mt=0; mt<2; mt++){
                    acc[mt][nt] = MFMA16(ah[mt], bh, acc[mt][nt]);   // hi*hi
                    acc[mt][nt] = MFMA16(ah[mt], bl, acc[mt][nt]);   // hi*lo
                    acc[mt][nt] = MFMA16(al[mt], bh, acc[mt][nt]);   // lo*hi
                }
            }
        }
    }
    // epilogue: D layout col=l15, row=quad*4+r
    #pragma unroll
    for (int nt=0; nt<3; nt++){
        const int n = wv*48 + nt*16 + l15;
        const int comp = n >> 6, c = n & 63;
        if (comp < 2) {
            unsigned short* dh = (comp==0) ? Qhi : Khi;
            unsigned short* dl = (comp==0) ? Qlo : Klo;
            #pragma unroll
            for (int mt=0; mt<2; mt++)
            #pragma unroll
            for (int r=0; r<4; r++){
                const int row = m0 + mt*16 + quad*4 + r;
                float v = acc[mt][nt][r];
                unsigned short h = f2bf(v);
                dh[(size_t)row*H_ + c] = h;
                dl[(size_t)row*H_ + c] = f2bf(v - bf2f(h));
            }
        } else {
            #pragma unroll
            for (int mt=0; mt<2; mt++){
                const int m = m0 + mt*16 + quad*4;   // 4 consecutive s (r)
                const int b = m >> 11, s0 = m & (S_-1);
                u16x4 pk;
                #pragma unroll
                for (int r=0;r<4;r++) pk[r] = f2bf(acc[mt][nt][r]);
                *(u16x4*)(Vt + (size_t)(b*H_ + c)*S_ + s0) = pk;
            }
        }
    }
}

// ---------------------------------------------------------------------------
// Kernel 2: mean of V per (b,h) — exact substitute for fully-masked rows
// (reference gives uniform softmax over ALL 2048 keys there).
// ---------------------------------------------------------------------------
__global__ __launch_bounds__(256) void meanv_kernel(const unsigned short* __restrict__ Vt,
                                                    float* __restrict__ meanV)
{
    int b = blockIdx.x >> 6, h = blockIdx.x & 63;
    const unsigned short* src = Vt + (size_t)b*H_*S_ + (size_t)h*S_;
    float sum = 0.f;
    for (int j = threadIdx.x; j < S_; j += 256) sum += bf2f(src[j]);
    #pragma unroll
    for (int m=32; m>=1; m>>=1) sum += __shfl_xor(sum, m);
    __shared__ float red[4];
    if ((threadIdx.x & 63) == 0) red[threadIdx.x >> 6] = sum;
    __syncthreads();
    if (threadIdx.x == 0) meanV[b*H_ + h] = (red[0]+red[1]+red[2]+red[3]) * (1.f/S_);
}

// ---------------------------------------------------------------------------
// Kernel 3: flash attention, split-K (flash-decoding).  Block = 64 q-rows
// (4 waves x 16), one split of TPS 64-key tiles.  Online softmax in fp32;
// QK^T with hi/lo bf16 (fp32-accurate logits); PV single bf16.
// Partials (m,l,O) to workspace; combine kernel merges.
// ---------------------------------------------------------------------------
__global__ __launch_bounds__(256) void attn_kernel(
    const unsigned short* __restrict__ Qhi, const unsigned short* __restrict__ Qlo,
    const unsigned short* __restrict__ Khi, const unsigned short* __restrict__ Klo,
    const unsigned short* __restrict__ Vt, const int* __restrict__ pad,
    float* __restrict__ Opart, float* __restrict__ mpart, float* __restrict__ lpart)
{
    const int qt = blockIdx.x, b = blockIdx.y, sp = blockIdx.z;
    const int t0 = sp * TPS;
    if (t0 > qt) return;                       // causal: tiles 0..qt only
    const int t1 = min(t0 + TPS, qt + 1);

    __shared__ unsigned short KtH[64*64], KtL[64*64], Vts[64*64];
    __shared__ unsigned short Ps[4][64*20];    // per-wave P^T scratch, stride 20
    __shared__ int pad_s[64];

    const int tid = threadIdx.x, lane = tid & 63, wv = tid >> 6, l15 = lane & 15, quad = lane >> 4;
    const int role = tid >> 6, srow = tid & 63;

    // Q fragments (A-operand: m=l15 row, k=quad*8+j), held in regs all kernel
    const size_t qrow = (size_t)(b*S_ + qt*64 + wv*16 + l15);
    bf16x8 aqh0 = *(const bf16x8*)(Qhi + qrow*H_ + quad*8);
    bf16x8 aqh1 = *(const bf16x8*)(Qhi + qrow*H_ + 32 + quad*8);
    bf16x8 aql0 = *(const bf16x8*)(Qlo + qrow*H_ + quad*8);
    bf16x8 aql1 = *(const bf16x8*)(Qlo + qrow*H_ + 32 + quad*8);

    float m_i[4], l_i[4];
    f32x4 o[4];
    #pragma unroll
    for (int r=0;r<4;r++){ m_i[r] = -INFINITY; l_i[r] = 0.f; }
    #pragma unroll
    for (int i=0;i<4;i++) o[i] = f32x4{0.f,0.f,0.f,0.f};

    const int qg = qt*64 + wv*16 + quad*4;     // + r = global q row
    unsigned short* Pw = &Ps[wv][0];

    for (int t = t0; t < t1; ++t) {
        const int kb = t * 64;
        __syncthreads();
        if (role < 3) {                        // stage KtH / KtL / Vts (one row/thread)
            const unsigned short* gs =
                (role==0) ? (Khi + ((size_t)(b*S_ + kb + srow))*H_) :
                (role==1) ? (Klo + ((size_t)(b*S_ + kb + srow))*H_) :
                            (Vt + (size_t)b*H_*S_ + (size_t)srow*S_ + kb);
            unsigned short* ld = (role==0) ? KtH : (role==1) ? KtL : Vts;
            #pragma unroll
            for (int i=0;i<8;i++){
                u16x8 d = ((const u16x8*)gs)[i];
                ((u16x8*)ld)[srow*8 + (i ^ (srow & 7))] = d;
            }
        } else {
            pad_s[srow] = pad[b*S_ + kb + srow];
        }
        __syncthreads();

        // --- S = Q K^T (hi/lo: fp32-accurate) ---
        f32x4 s[4];
        #pragma unroll
        for (int nt=0; nt<4; nt++){
            const int krw = nt*16 + l15;
            bf16x8 bh0 = ((const bf16x8*)KtH)[krw*8 + ((quad)   ^ (l15 & 7))];
            bf16x8 bh1 = ((const bf16x8*)KtH)[krw*8 + ((4+quad) ^ (l15 & 7))];
            bf16x8 bl0 = ((const bf16x8*)KtL)[krw*8 + ((quad)   ^ (l15 & 7))];
            bf16x8 bl1 = ((const bf16x8*)KtL)[krw*8 + ((4+quad) ^ (l15 & 7))];
            f32x4 z = f32x4{0.f,0.f,0.f,0.f};
            z = MFMA16(aqh0, bh0, z);
            z = MFMA16(aqh1, bh1, z);
            z = MFMA16(aqh0, bl0, z);
            z = MFMA16(aqh1, bl1, z);
            z = MFMA16(aql0, bh0, z);
            z = MFMA16(aql1, bh1, z);
            s[nt] = z;
        }
        // --- mask + scale (exactly like reference: -1e9/8 where invalid) ---
        float rmax[4] = {-INFINITY,-INFINITY,-INFINITY,-INFINITY};
        #pragma unroll
        for (int nt=0; nt<4; nt++){
            const int kcol = nt*16 + l15;
            const int kg = kb + kcol;
            const int pv = pad_s[kcol];
            #pragma unroll
            for (int r=0;r<4;r++){
                bool ok = (kg <= qg + r) && (pv != 0);
                float v = ok ? s[nt][r]*0.125f : -1.25e8f;
                s[nt][r] = v;
                rmax[r] = fmaxf(rmax[r], v);
            }
        }
        #pragma unroll
        for (int msk=1; msk<=8; msk<<=1){
            #pragma unroll
            for (int r=0;r<4;r++) rmax[r] = fmaxf(rmax[r], __shfl_xor(rmax[r], msk));
        }
        float alpha[4];
        #pragma unroll
        for (int r=0;r<4;r++){
            float mn = fmaxf(m_i[r], rmax[r]);
            alpha[r] = __expf(m_i[r] - mn);     // expf(-inf)=0 on first tile
            m_i[r] = mn;
        }
        float rsum[4] = {0.f,0.f,0.f,0.f};
        #pragma unroll
        for (int nt=0; nt<4; nt++)
        #pragma unroll
        for (int r=0;r<4;r++){
            float p = __expf(s[nt][r] - m_i[r]); // fully-masked row: exp(0)=1 (uniform)
            s[nt][r] = p;
            rsum[r] += p;
        }
        #pragma unroll
        for (int msk=1; msk<=8; msk<<=1){
            #pragma unroll
            for (int r=0;r<4;r++) rsum[r] += __shfl_xor(rsum[r], msk);
        }
        #pragma unroll
        for (int r=0;r<4;r++) l_i[r] = l_i[r]*alpha[r] + rsum[r];
        #pragma unroll
        for (int hnt=0; hnt<4; hnt++)
        #pragma unroll
        for (int r=0;r<4;r++) o[hnt][r] *= alpha[r];

        // --- P: C-layout -> A-layout via per-wave LDS [key][20] ---
        #pragma unroll
        for (int nt=0; nt<4; nt++){
            const int key = nt*16 + l15;
            u16x4 pk;
            #pragma unroll
            for (int r=0;r<4;r++) pk[r] = f2bf(s[nt][r]);
            *(u16x4*)(Pw + key*20 + quad*4) = pk;   // rows quad*4..+3 contiguous
        }
        // --- O += P V ---
        #pragma unroll
        for (int ks=0; ks<2; ks++){
            bf16x8 ap;
            #pragma unroll
            for (int j=0;j<8;j++) ap[j] = (short)Pw[(ks*32 + quad*8 + j)*20 + l15];
            #pragma unroll
            for (int hnt=0; hnt<4; hnt++){
                bf16x8 bv = ((const bf16x8*)Vts)[(hnt*16+l15)*8 + ((ks*4+quad) ^ (l15 & 7))];
                o[hnt] = MFMA16(ap, bv, o[hnt]);
            }
        }
    }
    // store partials: [b][qt][sp][row 64][h 64]
    const size_t rbase = ((size_t)((b*NQT + qt)*SPLITS + sp))*64 + wv*16 + quad*4;
    if (l15 == 0) {
        #pragma unroll
        for (int r=0;r<4;r++){ mpart[rbase + r] = m_i[r]; lpart[rbase + r] = l_i[r]; }
    }
    #pragma unroll
    for (int hnt=0; hnt<4; hnt++)
    #pragma unroll
    for (int r=0;r<4;r++)
        Opart[(rbase + r)*H_ + hnt*16 + l15] = o[hnt][r];
}

// ---------------------------------------------------------------------------
// Kernel 4: merge split-K partials.  One thread per output element.
// ---------------------------------------------------------------------------
__global__ __launch_bounds__(256) void combine_kernel(
    const float* __restrict__ Opart, const float* __restrict__ mpart,
    const float* __restrict__ lpart, const float* __restrict__ meanV,
    float* __restrict__ out)
{
    const int idx = blockIdx.x*256 + threadIdx.x;
    const int h = idx & 63;
    const int q = (idx >> 6) & (S_-1);
    const int b = idx >> 17;
    const int qt = q >> 6, r = q & 63;
    const int ns = (qt >> 2) + 1;              // ceil((qt+1)/TPS)
    const size_t rb = ((size_t)(b*NQT + qt)*SPLITS)*64 + r;
    float M = -INFINITY;
    for (int s2=0; s2<ns; s2++) M = fmaxf(M, mpart[rb + (size_t)s2*64]);
    float res;
    if (M == -1.25e8f) {                       // no valid key anywhere: uniform over all 2048
        res = meanV[b*H_ + h];
    } else {
        float L = 0.f, acc = 0.f;
        for (int s2=0; s2<ns; s2++){
            float mi = mpart[rb + (size_t)s2*64];
            float wgt = __expf(mi - M);
            L += wgt * lpart[rb + (size_t)s2*64];
            acc += wgt * Opart[(rb + (size_t)s2*64)*H_ + h];
        }
        res = acc / L;
    }
    out[idx] = res;
}

// ---------------------------------------------------------------------------
// Workspace layout (bytes):
//   0        Qhi  1 MB          4 MB   Vt    1 MB
//   1 MB     Qlo  1 MB          5 MB   Opart 16 MB (fp32 partials)
//   2 MB     Khi  1 MB         21 MB   mpart 256 KB ; 21.25MB lpart 256 KB
//   3 MB     Klo  1 MB         21.5MB meanV 1 KB
//  22 MB     WhiS 384 KB       22.5MB WloS  384 KB        total ~23 MB
// ---------------------------------------------------------------------------
extern "C" void kernel_launch(void* const* d_in, const int* in_sizes, int n_in,
                              void* d_out, int out_size, void* d_ws, size_t ws_size,
                              hipStream_t stream)
{
    (void)in_sizes; (void)n_in; (void)out_size; (void)ws_size;
    const float* x  = (const float*)d_in[0];
    const int* pad  = (const int*)d_in[1];
    const float* Wq = (const float*)d_in[2];
    const float* Wk = (const float*)d_in[3];
    const float* Wv = (const float*)d_in[4];
    float* out = (float*)d_out;
    char* ws = (char*)d_ws;
    const size_t MB = 1u << 20;
    unsigned short* Qhi = (unsigned short*)(ws + 0*MB);
    unsigned short* Qlo = (unsigned short*)(ws + 1*MB);
    unsigned short* Khi = (unsigned short*)(ws + 2*MB);
    unsigned short* Klo = (unsigned short*)(ws + 3*MB);
    unsigned short* Vt  = (unsigned short*)(ws + 4*MB);
    float* Opart = (float*)(ws + 5*MB);
    float* mpart = (float*)(ws + 21*MB);
    float* lpart = (float*)(ws + 21*MB + (1u<<18));
    float* meanV = (float*)(ws + 21*MB + 2*(1u<<18));
    unsigned short* WhiS = (unsigned short*)(ws + 22*MB);
    unsigned short* WloS = (unsigned short*)(ws + 22*MB + 512*1024);

    wprep_kernel<<<dim3(96), 256, 0, stream>>>(Wq, Wk, Wv, WhiS, WloS);
    qkv_kernel<<<dim3(256), 256, 0, stream>>>(x, WhiS, WloS, Qhi, Qlo, Khi, Klo, Vt);
    meanv_kernel<<<dim3(256), 256, 0, stream>>>(Vt, meanV);
    attn_kernel<<<dim3(NQT, B_, SPLITS), 256, 0, stream>>>(Qhi, Qlo, Khi, Klo, Vt, pad,
                                                           Opart, mpart, lpart);
    combine_kernel<<<dim3((B_*S_*H_)/256), 256, 0, stream>>>(Opart, mpart, lpart, meanV, out);
}